// Round 1
// baseline (355.890 us; speedup 1.0000x reference)
//
#include <hip/hip_runtime.h>

typedef __attribute__((ext_vector_type(8))) __bf16 bf16x8;
typedef __attribute__((ext_vector_type(4))) float f32x4;
typedef __attribute__((ext_vector_type(8))) unsigned short u16x8;

#define DEVFN static __device__ __forceinline__

DEVFN unsigned short f2bf(float f) {
  union { float f; unsigned int u; } v; v.f = f;
  unsigned int u = v.u;
  return (unsigned short)((u + 0x7fffu + ((u >> 16) & 1u)) >> 16);
}

DEVFN f32x4 mfma16(bf16x8 a, bf16x8 b, f32x4 c) {
  return __builtin_amdgcn_mfma_f32_16x16x32_bf16(a, b, c, 0, 0, 0);
}

DEVFN void gload16(const void* g, void* l) {
  __builtin_amdgcn_global_load_lds((const __attribute__((address_space(1))) void*)g,
                                   (__attribute__((address_space(3))) void*)l, 16, 0, 0);
}

// ---------------------------------------------------------------------------
// Convert a [R][1024] fp32 matrix to bf16 with per-row XOR-16B swizzle:
// byte' = byte ^ ((row&7)<<4)  (within each 128B block of the row)
// ---------------------------------------------------------------------------
__global__ __launch_bounds__(256) void cvt_swz_k(const float* __restrict__ in,
                                                 unsigned short* __restrict__ out) {
  int i = blockIdx.x * 256 + threadIdx.x;   // one thread = 8 elements
  int e0 = i << 3;
  int row = e0 >> 10, col0 = e0 & 1023;
  const float4* s = (const float4*)(in + ((size_t)row << 10) + col0);
  float4 a = s[0], b = s[1];
  u16x8 o;
  o[0] = f2bf(a.x); o[1] = f2bf(a.y); o[2] = f2bf(a.z); o[3] = f2bf(a.w);
  o[4] = f2bf(b.x); o[5] = f2bf(b.y); o[6] = f2bf(b.z); o[7] = f2bf(b.w);
  size_t ob = ((size_t)row << 11) + (size_t)((col0 << 1) ^ ((row & 7) << 4));
  *(u16x8*)((char*)out + ob) = o;
}

// ---------------------------------------------------------------------------
// Transpose+convert weight: W fp32 [1024 k][1024 n] -> Wt bf16 [n][k] swizzled
// ---------------------------------------------------------------------------
__global__ __launch_bounds__(256) void transW(const float* __restrict__ W,
                                              unsigned short* __restrict__ Wt) {
  __shared__ float t[64][65];
  int k0 = blockIdx.x * 64, n0 = blockIdx.y * 64;
  int tid = threadIdx.x;
#pragma unroll
  for (int it = 0; it < 4; ++it) {
    int r = it * 16 + (tid >> 4);
    int c = (tid & 15) * 4;
    float4 v = *(const float4*)(W + (size_t)(k0 + r) * 1024 + n0 + c);
    t[r][c] = v.x; t[r][c + 1] = v.y; t[r][c + 2] = v.z; t[r][c + 3] = v.w;
  }
  __syncthreads();
#pragma unroll
  for (int it = 0; it < 2; ++it) {
    int nl = it * 32 + (tid >> 3);
    int kc = tid & 7;
    u16x8 o;
#pragma unroll
    for (int j = 0; j < 8; ++j) o[j] = f2bf(t[kc * 8 + j][nl]);
    int n = n0 + nl;
    unsigned short* dst = (unsigned short*)((char*)Wt + (size_t)n * 2048 + (k0 << 1)
                                            + ((kc ^ (n & 7)) << 4));
    *(u16x8*)dst = o;
  }
}

// ---------------------------------------------------------------------------
// GEMM C[4096x1024] = A[4096x1024] * Bt[1024x1024]^T (+bias)*scale
// A, Bt bf16 row-swizzled. mode 0: write bf16 head-layout (B,H,S,64) swizzled.
// mode 1: write fp32 row-major.
// ---------------------------------------------------------------------------
__global__ __launch_bounds__(256, 2) void gemm_bf16(
    const unsigned short* __restrict__ A, const unsigned short* __restrict__ Bt,
    const float* __restrict__ bias, unsigned short* __restrict__ outH,
    float* __restrict__ outF, float scale, int mode) {
  constexpr int K = 1024, N = 1024;
  __shared__ unsigned short lA[128 * 64];
  __shared__ unsigned short lB[128 * 64];
  int tid = threadIdx.x, wave = tid >> 6, lane = tid & 63;
  int hi = lane >> 4, lo = lane & 15;
  int m0 = blockIdx.x * 128, n0 = blockIdx.y * 128;
  int wr = wave >> 1, wc = wave & 1;
  f32x4 zero = {0.f, 0.f, 0.f, 0.f};
  f32x4 acc[4][4];
#pragma unroll
  for (int mt = 0; mt < 4; ++mt)
#pragma unroll
    for (int nt = 0; nt < 4; ++nt) acc[mt][nt] = zero;

  for (int k0 = 0; k0 < K; k0 += 64) {
#pragma unroll
    for (int i = 0; i < 4; ++i) {
      int off = i * 4096 + tid * 16;
      int row = off >> 7, colb = off & 127;
      const char* g = (const char*)A + (size_t)(m0 + row) * 2048 + (k0 << 1) + colb;
      gload16(g, (char*)lA + i * 4096 + wave * 1024);
    }
#pragma unroll
    for (int i = 0; i < 4; ++i) {
      int off = i * 4096 + tid * 16;
      int row = off >> 7, colb = off & 127;
      const char* g = (const char*)Bt + (size_t)(n0 + row) * 2048 + (k0 << 1) + colb;
      gload16(g, (char*)lB + i * 4096 + wave * 1024);
    }
    __syncthreads();
#pragma unroll
    for (int kk = 0; kk < 2; ++kk) {
      bf16x8 af[4], bf[4];
#pragma unroll
      for (int mt = 0; mt < 4; ++mt) {
        int row = wr * 64 + mt * 16 + lo;
        int ob = (row << 7) + ((((kk << 2) + hi) << 4) ^ ((row & 7) << 4));
        af[mt] = *(const bf16x8*)((const char*)lA + ob);
      }
#pragma unroll
      for (int nt = 0; nt < 4; ++nt) {
        int row = wc * 64 + nt * 16 + lo;
        int ob = (row << 7) + ((((kk << 2) + hi) << 4) ^ ((row & 7) << 4));
        bf[nt] = *(const bf16x8*)((const char*)lB + ob);
      }
#pragma unroll
      for (int mt = 0; mt < 4; ++mt)
#pragma unroll
        for (int nt = 0; nt < 4; ++nt)
          acc[mt][nt] = mfma16(af[mt], bf[nt], acc[mt][nt]);
    }
    __syncthreads();
  }
  // epilogue
#pragma unroll
  for (int mt = 0; mt < 4; ++mt) {
#pragma unroll
    for (int nt = 0; nt < 4; ++nt) {
      int col = n0 + wc * 64 + nt * 16 + lo;
      float bs = bias[col];
#pragma unroll
      for (int j = 0; j < 4; ++j) {
        int row = m0 + wr * 64 + mt * 16 + (hi << 2) + j;
        float v = (acc[mt][nt][j] + bs) * scale;
        if (mode == 1) {
          outF[(size_t)row * N + col] = v;
        } else {
          size_t hb = ((size_t)((row >> 11) * 16 + (col >> 6))) << 18;  // head base bytes
          int ib = ((row & 2047) << 7) + ((col & 63) << 1);
          ib ^= (row & 7) << 4;
          *(unsigned short*)((char*)outH + hb + ib) = f2bf(v);
        }
      }
    }
  }
}

// ---------------------------------------------------------------------------
// Transpose V head-layout (B,H,S,64) swizzled -> (B,H,64,S) swizzled
// ---------------------------------------------------------------------------
__global__ __launch_bounds__(256) void transV(const unsigned short* __restrict__ vh,
                                              unsigned short* __restrict__ vt) {
  __shared__ unsigned short t[64][72];
  int k0 = blockIdx.x * 64;
  int bh = blockIdx.y;
  int tid = threadIdx.x;
  const char* head = (const char*)vh + ((size_t)bh << 18);
#pragma unroll
  for (int it = 0; it < 2; ++it) {
    int off = it * 4096 + tid * 16;
    int r = off >> 7, cb = off & 127;
    u16x8 v = *(const u16x8*)(head + (size_t)(k0 + r) * 128 + (cb ^ ((r & 7) << 4)));
    *(u16x8*)&t[r][cb >> 1] = v;
  }
  __syncthreads();
  char* ohead = (char*)vt + ((size_t)bh << 18);
#pragma unroll
  for (int it = 0; it < 2; ++it) {
    int d = it * 32 + (tid >> 3);
    int kc = tid & 7;
    u16x8 o;
#pragma unroll
    for (int j = 0; j < 8; ++j) o[j] = t[kc * 8 + j][d];
    *(u16x8*)(ohead + (size_t)d * 4096 + (k0 << 1) + ((kc ^ (d & 7)) << 4)) = o;
  }
}

// ---------------------------------------------------------------------------
// Fused attention: per block = 64 q rows of one (b,h). 2-pass flash:
// pass1 online max/denominator, pass2 recompute + write attn fp32 + PV.
// ---------------------------------------------------------------------------
__global__ __launch_bounds__(256, 2) void attn_k(
    const unsigned short* __restrict__ qh, const unsigned short* __restrict__ kh,
    const unsigned short* __restrict__ vt, const int* __restrict__ mask,
    float* __restrict__ attn, unsigned short* __restrict__ ctx) {
  constexpr int S = 2048;
  __shared__ unsigned short ktl[64 * 64];
  __shared__ unsigned short vtl[64 * 64];
  __shared__ unsigned long long mkb[32];
  __shared__ unsigned short pl[4][16 * 72];

  int tid = threadIdx.x, wave = tid >> 6, lane = tid & 63;
  int hi = lane >> 4, lo = lane & 15;
  int qb = blockIdx.x, bh = blockIdx.y;
  int b = bh >> 4, h = bh & 15;
  const char* khead = (const char*)kh + ((size_t)bh << 18);
  const char* qhead = (const char*)qh + ((size_t)bh << 18);
  const char* vhead = (const char*)vt + ((size_t)bh << 18);

  // mask bitset (2048 bits)
  for (int it = 0; it < 8; ++it) {
    int key = it * 256 + tid;
    unsigned long long bal = __ballot(mask[b * S + key] != 0);
    if (lane == 0) mkb[it * 4 + wave] = bal;
  }
  __syncthreads();

  int q0 = qb * 64 + wave * 16;
  bf16x8 qf[2];
  {
    int row = q0 + lo;
#pragma unroll
    for (int kk = 0; kk < 2; ++kk) {
      int ib = (row << 7) + ((((kk << 2) + hi) << 4) ^ ((row & 7) << 4));
      qf[kk] = *(const bf16x8*)(qhead + ib);
    }
  }

  float m_run[4], l_run[4];
#pragma unroll
  for (int j = 0; j < 4; ++j) { m_run[j] = -1e30f; l_run[j] = 0.f; }

  // ---- pass 1: statistics ----
  for (int kt = 0; kt < 32; ++kt) {
#pragma unroll
    for (int i = 0; i < 2; ++i) {
      const char* g = khead + (size_t)kt * 8192 + i * 4096 + tid * 16;
      gload16(g, (char*)ktl + i * 4096 + wave * 1024);
    }
    __syncthreads();
    unsigned long long mw = mkb[kt];
    f32x4 sv[4];
    bool ok[4];
#pragma unroll
    for (int nt = 0; nt < 4; ++nt) {
      int r = nt * 16 + lo;
      f32x4 a = {0.f, 0.f, 0.f, 0.f};
#pragma unroll
      for (int kk = 0; kk < 2; ++kk) {
        int ob = (r << 7) + ((((kk << 2) + hi) << 4) ^ ((r & 7) << 4));
        bf16x8 kf = *(const bf16x8*)((const char*)ktl + ob);
        a = mfma16(qf[kk], kf, a);
      }
      sv[nt] = a;
      ok[nt] = (mw >> (nt * 16 + lo)) & 1ull;
    }
#pragma unroll
    for (int j = 0; j < 4; ++j) {
      float mx = -1e30f;
#pragma unroll
      for (int nt = 0; nt < 4; ++nt) mx = fmaxf(mx, ok[nt] ? sv[nt][j] : -1e30f);
#pragma unroll
      for (int w = 1; w < 16; w <<= 1) mx = fmaxf(mx, __shfl_xor(mx, w));
      float mnew = fmaxf(m_run[j], mx);
      float ts = 0.f;
#pragma unroll
      for (int nt = 0; nt < 4; ++nt) ts += ok[nt] ? __expf(sv[nt][j] - mnew) : 0.f;
#pragma unroll
      for (int w = 1; w < 16; w <<= 1) ts += __shfl_xor(ts, w);
      l_run[j] = l_run[j] * __expf(m_run[j] - mnew) + ts;
      m_run[j] = mnew;
    }
    __syncthreads();
  }

  float rcp[4];
#pragma unroll
  for (int j = 0; j < 4; ++j) rcp[j] = l_run[j] > 0.f ? 1.0f / l_run[j] : 0.f;

  f32x4 cacc[4];
#pragma unroll
  for (int nt = 0; nt < 4; ++nt) cacc[nt] = (f32x4){0.f, 0.f, 0.f, 0.f};

  float* arow = attn + (size_t)bh * S * S;

  // ---- pass 2: recompute, write attention, PV ----
  for (int kt = 0; kt < 32; ++kt) {
#pragma unroll
    for (int i = 0; i < 2; ++i) {
      const char* g = khead + (size_t)kt * 8192 + i * 4096 + tid * 16;
      gload16(g, (char*)ktl + i * 4096 + wave * 1024);
    }
#pragma unroll
    for (int i = 0; i < 2; ++i) {
      int off = i * 4096 + tid * 16;
      int d = off >> 7, x = off & 127;
      const char* g = vhead + (size_t)d * 4096 + kt * 128 + x;
      gload16(g, (char*)vtl + i * 4096 + wave * 1024);
    }
    __syncthreads();
    unsigned long long mw = mkb[kt];
    float pe[4][4];
#pragma unroll
    for (int nt = 0; nt < 4; ++nt) {
      int r = nt * 16 + lo;
      f32x4 a = {0.f, 0.f, 0.f, 0.f};
#pragma unroll
      for (int kk = 0; kk < 2; ++kk) {
        int ob = (r << 7) + ((((kk << 2) + hi) << 4) ^ ((r & 7) << 4));
        bf16x8 kf = *(const bf16x8*)((const char*)ktl + ob);
        a = mfma16(qf[kk], kf, a);
      }
      bool ok = (mw >> (nt * 16 + lo)) & 1ull;
#pragma unroll
      for (int j = 0; j < 4; ++j) pe[nt][j] = ok ? __expf(a[j] - m_run[j]) : 0.f;
    }
    // write attention (normalized) + stage P into LDS (unnormalized)
#pragma unroll
    for (int nt = 0; nt < 4; ++nt) {
#pragma unroll
      for (int j = 0; j < 4; ++j) {
        int qr = q0 + (hi << 2) + j;
        int kg = kt * 64 + nt * 16 + lo;
        arow[(size_t)qr * S + kg] = pe[nt][j] * rcp[j];
        pl[wave][((hi << 2) + j) * 72 + nt * 16 + lo] = f2bf(pe[nt][j]);
      }
    }
    asm volatile("s_waitcnt lgkmcnt(0)" ::: "memory");
    __builtin_amdgcn_sched_barrier(0);
    // PV: cacc[nt_d] += P(16x32 chunk) * V(32x16)
#pragma unroll
    for (int c = 0; c < 2; ++c) {
      bf16x8 pa = *(const bf16x8*)&pl[wave][lo * 72 + c * 32 + hi * 8];
#pragma unroll
      for (int nt = 0; nt < 4; ++nt) {
        int d = nt * 16 + lo;
        int ob = (d << 7) + ((((c << 2) + hi) << 4) ^ ((d & 7) << 4));
        bf16x8 vf = *(const bf16x8*)((const char*)vtl + ob);
        cacc[nt] = mfma16(pa, vf, cacc[nt]);
      }
    }
    __syncthreads();
  }

  // write context bf16, layout (B,S,1024) row-swizzled
#pragma unroll
  for (int nt = 0; nt < 4; ++nt) {
#pragma unroll
    for (int j = 0; j < 4; ++j) {
      int s = q0 + (hi << 2) + j;
      int mrow = b * S + s;
      int n = h * 64 + nt * 16 + lo;
      float v = cacc[nt][j] * rcp[j];
      int ib = (n << 1) ^ ((mrow & 7) << 4);
      *(unsigned short*)((char*)ctx + (size_t)mrow * 2048 + ib) = f2bf(v);
    }
  }
}

// ---------------------------------------------------------------------------
extern "C" void kernel_launch(void* const* d_in, const int* in_sizes, int n_in,
                              void* d_out, int out_size, void* d_ws, size_t ws_size,
                              hipStream_t stream) {
  const float* Q  = (const float*)d_in[0];
  const float* K  = (const float*)d_in[1];
  const float* V  = (const float*)d_in[2];
  const int* mask = (const int*)d_in[3];
  const float* WQ = (const float*)d_in[4];
  const float* bQ = (const float*)d_in[5];
  const float* WK = (const float*)d_in[6];
  const float* bK = (const float*)d_in[7];
  const float* WV = (const float*)d_in[8];
  const float* bV = (const float*)d_in[9];
  const float* WO = (const float*)d_in[10];
  const float* bO = (const float*)d_in[11];

  char* ws = (char*)d_ws;
  const size_t M1 = 1ull << 20;
  unsigned short* WQt = (unsigned short*)(ws + 0 * M1);
  unsigned short* WKt = (unsigned short*)(ws + 2 * M1);
  unsigned short* WVt = (unsigned short*)(ws + 4 * M1);
  unsigned short* WOt = (unsigned short*)(ws + 6 * M1);
  unsigned short* qh  = (unsigned short*)(ws + 8 * M1);
  unsigned short* kh  = (unsigned short*)(ws + 16 * M1);
  unsigned short* Qb  = (unsigned short*)(ws + 24 * M1);
  unsigned short* Kb  = (unsigned short*)(ws + 32 * M1);
  unsigned short* Vb  = (unsigned short*)(ws + 40 * M1);
  unsigned short* vh  = (unsigned short*)(ws + 24 * M1);  // alias Qb (free after gemm q)
  unsigned short* vt  = (unsigned short*)(ws + 32 * M1);  // alias Kb (free after gemm k)
  unsigned short* ctx = (unsigned short*)(ws + 40 * M1);  // alias Vb (free after gemm v)

  float* outF = (float*)d_out;                 // (B,S,1024)
  float* attn = (float*)d_out + 4194304;       // (B,H,S,S)

  dim3 blk(256);
  cvt_swz_k<<<2048, blk, 0, stream>>>(Q, Qb);
  cvt_swz_k<<<2048, blk, 0, stream>>>(K, Kb);
  cvt_swz_k<<<2048, blk, 0, stream>>>(V, Vb);
  transW<<<dim3(16, 16), blk, 0, stream>>>(WQ, WQt);
  transW<<<dim3(16, 16), blk, 0, stream>>>(WK, WKt);
  transW<<<dim3(16, 16), blk, 0, stream>>>(WV, WVt);
  transW<<<dim3(16, 16), blk, 0, stream>>>(WO, WOt);
  gemm_bf16<<<dim3(32, 8), blk, 0, stream>>>(Qb, WQt, bQ, qh, nullptr, 0.125f, 0);
  gemm_bf16<<<dim3(32, 8), blk, 0, stream>>>(Kb, WKt, bK, kh, nullptr, 1.f, 0);
  gemm_bf16<<<dim3(32, 8), blk, 0, stream>>>(Vb, WVt, bV, vh, nullptr, 1.f, 0);
  transV<<<dim3(32, 32), blk, 0, stream>>>(vh, vt);
  attn_k<<<dim3(32, 32), blk, 0, stream>>>(qh, kh, vt, mask, attn, ctx);
  gemm_bf16<<<dim3(32, 8), blk, 0, stream>>>(ctx, WOt, bO, nullptr, outF, 1.f, 1);
}

// Round 2
// 353.088 us; speedup vs baseline: 1.0079x; 1.0079x over previous
//
#include <hip/hip_runtime.h>

typedef __attribute__((ext_vector_type(8))) __bf16 bf16x8;
typedef __attribute__((ext_vector_type(4))) float f32x4;
typedef __attribute__((ext_vector_type(8))) unsigned short u16x8;

#define DEVFN static __device__ __forceinline__

#if __has_builtin(__builtin_amdgcn_exp2f)
#define EXP2(x) __builtin_amdgcn_exp2f(x)
#else
#define EXP2(x) exp2f(x)
#endif

DEVFN f32x4 mfma16(bf16x8 a, bf16x8 b, f32x4 c) {
  return __builtin_amdgcn_mfma_f32_16x16x32_bf16(a, b, c, 0, 0, 0);
}

DEVFN void gload16(const void* g, void* l) {
  __builtin_amdgcn_global_load_lds((const __attribute__((address_space(1))) void*)g,
                                   (__attribute__((address_space(3))) void*)l, 16, 0, 0);
}

// ---------------------------------------------------------------------------
// fp32 [R][1024] -> bf16 row-swizzled (byte ^= (row&7)<<4 within 128B blocks)
// z selects (s0,d0) or (s1,d1).
// ---------------------------------------------------------------------------
__global__ __launch_bounds__(256) void cvt2_k(const float* __restrict__ s0,
                                              unsigned short* __restrict__ d0,
                                              const float* __restrict__ s1,
                                              unsigned short* __restrict__ d1) {
  const float* in = blockIdx.z ? s1 : s0;
  unsigned short* out = blockIdx.z ? d1 : d0;
  int i = blockIdx.x * 256 + threadIdx.x;
  int e0 = i << 3;
  int row = e0 >> 10, col0 = e0 & 1023;
  const float4* s = (const float4*)(in + ((size_t)row << 10) + col0);
  float4 a = s[0], b = s[1];
  bf16x8 o;
  o[0] = (__bf16)a.x; o[1] = (__bf16)a.y; o[2] = (__bf16)a.z; o[3] = (__bf16)a.w;
  o[4] = (__bf16)b.x; o[5] = (__bf16)b.y; o[6] = (__bf16)b.z; o[7] = (__bf16)b.w;
  size_t ob = ((size_t)row << 11) + (size_t)((col0 << 1) ^ ((row & 7) << 4));
  *(bf16x8*)((char*)out + ob) = o;
}

// ---------------------------------------------------------------------------
// Transpose+convert weights: W fp32 [1024 k][1024 n] -> Wt bf16 [n][k] swizzled
// z = 0..3 picks w0..w3, output at ob + z*2MB.
// ---------------------------------------------------------------------------
__global__ __launch_bounds__(256) void transW4(const float* __restrict__ w0,
                                               const float* __restrict__ w1,
                                               const float* __restrict__ w2,
                                               const float* __restrict__ w3,
                                               unsigned short* __restrict__ obase) {
  __shared__ float t[64][65];
  const float* W = blockIdx.z == 0 ? w0 : blockIdx.z == 1 ? w1 : blockIdx.z == 2 ? w2 : w3;
  unsigned short* Wt = obase + ((size_t)blockIdx.z << 20);
  int k0 = blockIdx.x * 64, n0 = blockIdx.y * 64;
  int tid = threadIdx.x;
#pragma unroll
  for (int it = 0; it < 4; ++it) {
    int r = it * 16 + (tid >> 4);
    int c = (tid & 15) * 4;
    float4 v = *(const float4*)(W + (size_t)(k0 + r) * 1024 + n0 + c);
    t[r][c] = v.x; t[r][c + 1] = v.y; t[r][c + 2] = v.z; t[r][c + 3] = v.w;
  }
  __syncthreads();
#pragma unroll
  for (int it = 0; it < 2; ++it) {
    int nl = it * 32 + (tid >> 3);
    int kc = tid & 7;
    bf16x8 o;
#pragma unroll
    for (int j = 0; j < 8; ++j) o[j] = (__bf16)t[kc * 8 + j][nl];
    int n = n0 + nl;
    char* dst = (char*)Wt + (size_t)n * 2048 + (k0 << 1) + ((kc ^ (n & 7)) << 4);
    *(bf16x8*)dst = o;
  }
}

// ---------------------------------------------------------------------------
// Templated GEMM C[4096xBN-block] = A[4096x1024] * Bt[1024x1024]^T (+bias)*scale
// MODE 0: bf16 head-layout (B,H,S,64) swizzled. MODE 1: fp32 row-major.
// blockIdx.z selects arg set (fused launches).
// ---------------------------------------------------------------------------
struct GArg {
  const unsigned short* A;
  const unsigned short* Bt;
  const float* bias;
  unsigned short* outH;
  float* outF;
  float scale;
};

template <int BM, int BN, int WR, int WC, int MODE>
__global__ __launch_bounds__(256, 2) void gemm_t(GArg g0, GArg g1) {
  GArg g = (blockIdx.z == 0) ? g0 : g1;
  constexpr int MT = BM / WR / 16, NT = BN / WC / 16;
  __shared__ unsigned short lA[BM * 64];
  __shared__ unsigned short lB[BN * 64];
  int tid = threadIdx.x, wave = tid >> 6, lane = tid & 63;
  int hi = lane >> 4, lo = lane & 15;
  int m0 = blockIdx.x * BM, n0 = blockIdx.y * BN;
  int wr = wave / WC, wc = wave % WC;
  f32x4 acc[MT][NT];
#pragma unroll
  for (int mt = 0; mt < MT; ++mt)
#pragma unroll
    for (int nt = 0; nt < NT; ++nt) acc[mt][nt] = (f32x4){0.f, 0.f, 0.f, 0.f};

  for (int k0 = 0; k0 < 1024; k0 += 64) {
#pragma unroll
    for (int i = 0; i < BM / 32; ++i) {
      int off = i * 4096 + tid * 16;
      int row = off >> 7, colb = off & 127;
      gload16((const char*)g.A + (size_t)(m0 + row) * 2048 + (k0 << 1) + colb,
              (char*)lA + i * 4096 + wave * 1024);
    }
#pragma unroll
    for (int i = 0; i < BN / 32; ++i) {
      int off = i * 4096 + tid * 16;
      int row = off >> 7, colb = off & 127;
      gload16((const char*)g.Bt + (size_t)(n0 + row) * 2048 + (k0 << 1) + colb,
              (char*)lB + i * 4096 + wave * 1024);
    }
    __syncthreads();
#pragma unroll
    for (int kk = 0; kk < 2; ++kk) {
      bf16x8 af[MT], bfr[NT];
#pragma unroll
      for (int mt = 0; mt < MT; ++mt) {
        int row = wr * (BM / WR) + mt * 16 + lo;
        int ob = (row << 7) + ((((kk << 2) + hi) << 4) ^ ((row & 7) << 4));
        af[mt] = *(const bf16x8*)((const char*)lA + ob);
      }
#pragma unroll
      for (int nt = 0; nt < NT; ++nt) {
        int row = wc * (BN / WC) + nt * 16 + lo;
        int ob = (row << 7) + ((((kk << 2) + hi) << 4) ^ ((row & 7) << 4));
        bfr[nt] = *(const bf16x8*)((const char*)lB + ob);
      }
#pragma unroll
      for (int mt = 0; mt < MT; ++mt)
#pragma unroll
        for (int nt = 0; nt < NT; ++nt)
          acc[mt][nt] = mfma16(af[mt], bfr[nt], acc[mt][nt]);
    }
    __syncthreads();
  }
#pragma unroll
  for (int mt = 0; mt < MT; ++mt) {
#pragma unroll
    for (int nt = 0; nt < NT; ++nt) {
      int col = n0 + wc * (BN / WC) + nt * 16 + lo;
      float bs = g.bias[col];
#pragma unroll
      for (int j = 0; j < 4; ++j) {
        int row = m0 + wr * (BM / WR) + mt * 16 + (hi << 2) + j;
        float v = (acc[mt][nt][j] + bs) * g.scale;
        if (MODE == 1) {
          g.outF[(size_t)row * 1024 + col] = v;
        } else {
          size_t hb = ((size_t)((row >> 11) * 16 + (col >> 6))) << 18;
          int ib = ((row & 2047) << 7) + ((col & 63) << 1);
          ib ^= (row & 7) << 4;
          *(__bf16*)((char*)g.outH + hb + ib) = (__bf16)v;
        }
      }
    }
  }
}

// ---------------------------------------------------------------------------
// Transpose V head-layout (B,H,S,64) swizzled -> (B,H,64,S) swizzled
// ---------------------------------------------------------------------------
__global__ __launch_bounds__(256) void transV(const unsigned short* __restrict__ vh,
                                              unsigned short* __restrict__ vt) {
  __shared__ unsigned short t[64][72];
  int k0 = blockIdx.x * 64;
  int bh = blockIdx.y;
  int tid = threadIdx.x;
  const char* head = (const char*)vh + ((size_t)bh << 18);
#pragma unroll
  for (int it = 0; it < 2; ++it) {
    int off = it * 4096 + tid * 16;
    int r = off >> 7, cb = off & 127;
    u16x8 v = *(const u16x8*)(head + (size_t)(k0 + r) * 128 + (cb ^ ((r & 7) << 4)));
    *(u16x8*)&t[r][cb >> 1] = v;
  }
  __syncthreads();
  char* ohead = (char*)vt + ((size_t)bh << 18);
#pragma unroll
  for (int it = 0; it < 2; ++it) {
    int d = it * 32 + (tid >> 3);
    int kc = tid & 7;
    u16x8 o;
#pragma unroll
    for (int j = 0; j < 8; ++j) o[j] = t[kc * 8 + j][d];
    *(u16x8*)(ohead + (size_t)d * 4096 + (k0 << 1) + ((kc ^ (d & 7)) << 4)) = o;
  }
}

// ---------------------------------------------------------------------------
// Fused attention, no-max-stabilization (any per-row constant cancels; scores
// are O(5) here so exp2 in fp32 is safe). Scores arrive pre-scaled by
// log2(e)/sqrt(64) (folded into Q projection).
// pass1: row sums only (per-lane accumulate, one reduce at end).
// pass2: recompute, write normalized attn fp32 (nontemporal), PV via LDS P.
// ---------------------------------------------------------------------------
__global__ __launch_bounds__(256, 2) void attn_k(
    const unsigned short* __restrict__ qh, const unsigned short* __restrict__ kh,
    const unsigned short* __restrict__ vt, const int* __restrict__ mask,
    float* __restrict__ attn, unsigned short* __restrict__ ctx) {
  constexpr int S = 2048;
  __shared__ unsigned short ktl[64 * 64];
  __shared__ unsigned short vtl[64 * 64];
  __shared__ unsigned long long mkb[32];
  __shared__ __bf16 pl[4][16 * 72];

  int tid = threadIdx.x, wave = tid >> 6, lane = tid & 63;
  int hi = lane >> 4, lo = lane & 15;
  // bijective XCD swizzle: each XCD keeps 4 heads' K/V resident in its L2
  int f = blockIdx.y * 32 + blockIdx.x;
  int xcd = f & 7, slot = f >> 3;
  int bh = xcd * 4 + (slot & 3);
  int qb = slot >> 2;
  int b = bh >> 4, h = bh & 15;
  const char* khead = (const char*)kh + ((size_t)bh << 18);
  const char* qhead = (const char*)qh + ((size_t)bh << 18);
  const char* vhead = (const char*)vt + ((size_t)bh << 18);

  for (int it = 0; it < 8; ++it) {
    unsigned long long bal = __ballot(mask[b * S + it * 256 + tid] != 0);
    if (lane == 0) mkb[it * 4 + wave] = bal;
  }
  __syncthreads();

  int q0 = qb * 64 + wave * 16;
  bf16x8 qf[2];
  {
    int row = q0 + lo;
#pragma unroll
    for (int kk = 0; kk < 2; ++kk) {
      int ib = (row << 7) + ((((kk << 2) + hi) << 4) ^ ((row & 7) << 4));
      qf[kk] = *(const bf16x8*)(qhead + ib);
    }
  }

  float lsum[4] = {0.f, 0.f, 0.f, 0.f};

  // ---- pass 1: row sums ----
  for (int kt = 0; kt < 32; ++kt) {
#pragma unroll
    for (int i = 0; i < 2; ++i)
      gload16(khead + (size_t)kt * 8192 + i * 4096 + tid * 16,
              (char*)ktl + i * 4096 + wave * 1024);
    __syncthreads();
    unsigned long long mw = mkb[kt];
#pragma unroll
    for (int nt = 0; nt < 4; ++nt) {
      int r = nt * 16 + lo;
      f32x4 a = {0.f, 0.f, 0.f, 0.f};
#pragma unroll
      for (int kk = 0; kk < 2; ++kk) {
        int ob = (r << 7) + ((((kk << 2) + hi) << 4) ^ ((r & 7) << 4));
        a = mfma16(qf[kk], *(const bf16x8*)((const char*)ktl + ob), a);
      }
      bool ok = (mw >> r) & 1ull;
#pragma unroll
      for (int j = 0; j < 4; ++j) lsum[j] += ok ? EXP2(a[j]) : 0.f;
    }
    __syncthreads();
  }

  float rcp[4];
#pragma unroll
  for (int j = 0; j < 4; ++j) {
    float s = lsum[j];
    s += __shfl_xor(s, 1); s += __shfl_xor(s, 2);
    s += __shfl_xor(s, 4); s += __shfl_xor(s, 8);
    rcp[j] = s > 0.f ? 1.0f / s : 0.f;
  }

  f32x4 cacc[4];
#pragma unroll
  for (int nt = 0; nt < 4; ++nt) cacc[nt] = (f32x4){0.f, 0.f, 0.f, 0.f};

  float* arow = attn + (size_t)bh * S * S;

  // ---- pass 2: recompute, write normalized attn, PV ----
  for (int kt = 0; kt < 32; ++kt) {
#pragma unroll
    for (int i = 0; i < 2; ++i)
      gload16(khead + (size_t)kt * 8192 + i * 4096 + tid * 16,
              (char*)ktl + i * 4096 + wave * 1024);
#pragma unroll
    for (int i = 0; i < 2; ++i) {
      int off = i * 4096 + tid * 16;
      int d = off >> 7, x = off & 127;
      gload16(vhead + (size_t)d * 4096 + kt * 128 + x,
              (char*)vtl + i * 4096 + wave * 1024);
    }
    __syncthreads();
    unsigned long long mw = mkb[kt];
#pragma unroll
    for (int nt = 0; nt < 4; ++nt) {
      int r = nt * 16 + lo;
      f32x4 a = {0.f, 0.f, 0.f, 0.f};
#pragma unroll
      for (int kk = 0; kk < 2; ++kk) {
        int ob = (r << 7) + ((((kk << 2) + hi) << 4) ^ ((r & 7) << 4));
        a = mfma16(qf[kk], *(const bf16x8*)((const char*)ktl + ob), a);
      }
      bool ok = (mw >> r) & 1ull;
#pragma unroll
      for (int j = 0; j < 4; ++j) {
        float pn = ok ? EXP2(a[j]) * rcp[j] : 0.f;
        int qr = q0 + (hi << 2) + j;
        __builtin_nontemporal_store(pn, &arow[(size_t)qr * S + kt * 64 + r]);
        pl[wave][((hi << 2) + j) * 72 + r] = (__bf16)pn;
      }
    }
    asm volatile("s_waitcnt lgkmcnt(0)" ::: "memory");
    __builtin_amdgcn_sched_barrier(0);
#pragma unroll
    for (int c = 0; c < 2; ++c) {
      bf16x8 pa = *(const bf16x8*)&pl[wave][lo * 72 + c * 32 + hi * 8];
#pragma unroll
      for (int nt = 0; nt < 4; ++nt) {
        int d = nt * 16 + lo;
        int ob = (d << 7) + ((((c << 2) + hi) << 4) ^ ((d & 7) << 4));
        cacc[nt] = mfma16(pa, *(const bf16x8*)((const char*)vtl + ob), cacc[nt]);
      }
    }
    __syncthreads();
  }

  // context write, layout (B,S,1024) row-swizzled bf16 (already normalized)
#pragma unroll
  for (int nt = 0; nt < 4; ++nt) {
#pragma unroll
    for (int j = 0; j < 4; ++j) {
      int s = q0 + (hi << 2) + j;
      int mrow = b * S + s;
      int n = h * 64 + nt * 16 + lo;
      int ib = (n << 1) ^ ((mrow & 7) << 4);
      *(__bf16*)((char*)ctx + (size_t)mrow * 2048 + ib) = (__bf16)cacc[nt][j];
    }
  }
}

// ---------------------------------------------------------------------------
extern "C" void kernel_launch(void* const* d_in, const int* in_sizes, int n_in,
                              void* d_out, int out_size, void* d_ws, size_t ws_size,
                              hipStream_t stream) {
  const float* Q  = (const float*)d_in[0];
  const float* K  = (const float*)d_in[1];
  const float* V  = (const float*)d_in[2];
  const int* mask = (const int*)d_in[3];
  const float* WQ = (const float*)d_in[4];
  const float* bQ = (const float*)d_in[5];
  const float* WK = (const float*)d_in[6];
  const float* bK = (const float*)d_in[7];
  const float* WV = (const float*)d_in[8];
  const float* bV = (const float*)d_in[9];
  const float* WO = (const float*)d_in[10];
  const float* bO = (const float*)d_in[11];

  char* ws = (char*)d_ws;
  const size_t M1 = 1ull << 20;
  unsigned short* WQt = (unsigned short*)(ws + 0 * M1);
  unsigned short* WKt = (unsigned short*)(ws + 2 * M1);
  unsigned short* WVt = (unsigned short*)(ws + 4 * M1);
  unsigned short* WOt = (unsigned short*)(ws + 6 * M1);
  unsigned short* qh  = (unsigned short*)(ws + 8 * M1);
  unsigned short* kh  = (unsigned short*)(ws + 16 * M1);
  unsigned short* vh  = (unsigned short*)(ws + 24 * M1);
  unsigned short* Qb  = (unsigned short*)(ws + 32 * M1);
  unsigned short* Kb  = (unsigned short*)(ws + 40 * M1);
  // aliases (stream-ordered reuse; total ws footprint stays at 48 MB)
  unsigned short* Vb  = (unsigned short*)(ws + 32 * M1);  // after gemmQK (Qb dead)
  unsigned short* vt  = (unsigned short*)(ws + 40 * M1);  // after gemmQK (Kb dead)
  unsigned short* ctx = (unsigned short*)(ws + 32 * M1);  // after gemmV (Vb dead)

  float* outF = (float*)d_out;                 // (B,S,1024) fp32
  float* attn = (float*)d_out + 4194304;       // (B,H,S,S) fp32

  dim3 blk(256);
  // scale folds 1/sqrt(d_k) * log2(e) into q so softmax uses raw v_exp_f32
  const float qscale = 0.125f * 1.44269504088896340736f;

  cvt2_k<<<dim3(2048, 1, 2), blk, 0, stream>>>(Q, Qb, K, Kb);
  transW4<<<dim3(16, 16, 4), blk, 0, stream>>>(WQ, WK, WV, WO, WQt);

  GArg aq{Qb, WQt, bQ, qh, nullptr, qscale};
  GArg ak{Kb, WKt, bK, kh, nullptr, 1.f};
  gemm_t<128, 128, 2, 2, 0><<<dim3(32, 8, 2), blk, 0, stream>>>(aq, ak);

  cvt2_k<<<dim3(2048, 1, 1), blk, 0, stream>>>(V, Vb, V, Vb);

  GArg av{Vb, WVt, bV, vh, nullptr, 1.f};
  gemm_t<64, 128, 1, 4, 0><<<dim3(64, 8, 1), blk, 0, stream>>>(av, av);

  transV<<<dim3(32, 32), blk, 0, stream>>>(vh, vt);

  attn_k<<<dim3(32, 32), blk, 0, stream>>>(qh, kh, vt, mask, attn, ctx);

  GArg ao{ctx, WOt, bO, nullptr, outF, 1.f};
  gemm_t<64, 128, 1, 4, 1><<<dim3(64, 8, 1), blk, 0, stream>>>(ao, ao);
}

// Round 3
// 341.677 us; speedup vs baseline: 1.0416x; 1.0334x over previous
//
#include <hip/hip_runtime.h>

typedef __attribute__((ext_vector_type(8))) __bf16 bf16x8;
typedef __attribute__((ext_vector_type(4))) float f32x4;
typedef __attribute__((ext_vector_type(8))) unsigned short u16x8;

#define DEVFN static __device__ __forceinline__

#if __has_builtin(__builtin_amdgcn_exp2f)
#define EXP2(x) __builtin_amdgcn_exp2f(x)
#else
#define EXP2(x) exp2f(x)
#endif

DEVFN f32x4 mfma16(bf16x8 a, bf16x8 b, f32x4 c) {
  return __builtin_amdgcn_mfma_f32_16x16x32_bf16(a, b, c, 0, 0, 0);
}

DEVFN void gload16(const void* g, void* l) {
  __builtin_amdgcn_global_load_lds((const __attribute__((address_space(1))) void*)g,
                                   (__attribute__((address_space(3))) void*)l, 16, 0, 0);
}

// ---------------------------------------------------------------------------
// fp32 [R][1024] -> bf16 row-swizzled (byte ^= (row&7)<<4 within 128B blocks)
// ---------------------------------------------------------------------------
__global__ __launch_bounds__(256) void cvt2_k(const float* __restrict__ s0,
                                              unsigned short* __restrict__ d0,
                                              const float* __restrict__ s1,
                                              unsigned short* __restrict__ d1) {
  const float* in = blockIdx.z ? s1 : s0;
  unsigned short* out = blockIdx.z ? d1 : d0;
  int i = blockIdx.x * 256 + threadIdx.x;
  int e0 = i << 3;
  int row = e0 >> 10, col0 = e0 & 1023;
  const float4* s = (const float4*)(in + ((size_t)row << 10) + col0);
  float4 a = s[0], b = s[1];
  bf16x8 o;
  o[0] = (__bf16)a.x; o[1] = (__bf16)a.y; o[2] = (__bf16)a.z; o[3] = (__bf16)a.w;
  o[4] = (__bf16)b.x; o[5] = (__bf16)b.y; o[6] = (__bf16)b.z; o[7] = (__bf16)b.w;
  size_t ob = ((size_t)row << 11) + (size_t)((col0 << 1) ^ ((row & 7) << 4));
  *(bf16x8*)((char*)out + ob) = o;
}

// ---------------------------------------------------------------------------
// Transpose+convert weights: W fp32 [1024 k][1024 n] -> Wt bf16 [n][k] swizzled
// ---------------------------------------------------------------------------
__global__ __launch_bounds__(256) void transW4(const float* __restrict__ w0,
                                               const float* __restrict__ w1,
                                               const float* __restrict__ w2,
                                               const float* __restrict__ w3,
                                               unsigned short* __restrict__ obase) {
  __shared__ float t[64][65];
  const float* W = blockIdx.z == 0 ? w0 : blockIdx.z == 1 ? w1 : blockIdx.z == 2 ? w2 : w3;
  unsigned short* Wt = obase + ((size_t)blockIdx.z << 20);
  int k0 = blockIdx.x * 64, n0 = blockIdx.y * 64;
  int tid = threadIdx.x;
#pragma unroll
  for (int it = 0; it < 4; ++it) {
    int r = it * 16 + (tid >> 4);
    int c = (tid & 15) * 4;
    float4 v = *(const float4*)(W + (size_t)(k0 + r) * 1024 + n0 + c);
    t[r][c] = v.x; t[r][c + 1] = v.y; t[r][c + 2] = v.z; t[r][c + 3] = v.w;
  }
  __syncthreads();
#pragma unroll
  for (int it = 0; it < 2; ++it) {
    int nl = it * 32 + (tid >> 3);
    int kc = tid & 7;
    bf16x8 o;
#pragma unroll
    for (int j = 0; j < 8; ++j) o[j] = (__bf16)t[kc * 8 + j][nl];
    int n = n0 + nl;
    char* dst = (char*)Wt + (size_t)n * 2048 + (k0 << 1) + ((kc ^ (n & 7)) << 4);
    *(bf16x8*)dst = o;
  }
}

// ---------------------------------------------------------------------------
// Templated GEMM (unchanged from R2)
// ---------------------------------------------------------------------------
struct GArg {
  const unsigned short* A;
  const unsigned short* Bt;
  const float* bias;
  unsigned short* outH;
  float* outF;
  float scale;
};

template <int BM, int BN, int WR, int WC, int MODE>
__global__ __launch_bounds__(256, 2) void gemm_t(GArg g0, GArg g1) {
  GArg g = (blockIdx.z == 0) ? g0 : g1;
  constexpr int MT = BM / WR / 16, NT = BN / WC / 16;
  __shared__ unsigned short lA[BM * 64];
  __shared__ unsigned short lB[BN * 64];
  int tid = threadIdx.x, wave = tid >> 6, lane = tid & 63;
  int hi = lane >> 4, lo = lane & 15;
  int m0 = blockIdx.x * BM, n0 = blockIdx.y * BN;
  int wr = wave / WC, wc = wave % WC;
  f32x4 acc[MT][NT];
#pragma unroll
  for (int mt = 0; mt < MT; ++mt)
#pragma unroll
    for (int nt = 0; nt < NT; ++nt) acc[mt][nt] = (f32x4){0.f, 0.f, 0.f, 0.f};

  for (int k0 = 0; k0 < 1024; k0 += 64) {
#pragma unroll
    for (int i = 0; i < BM / 32; ++i) {
      int off = i * 4096 + tid * 16;
      int row = off >> 7, colb = off & 127;
      gload16((const char*)g.A + (size_t)(m0 + row) * 2048 + (k0 << 1) + colb,
              (char*)lA + i * 4096 + wave * 1024);
    }
#pragma unroll
    for (int i = 0; i < BN / 32; ++i) {
      int off = i * 4096 + tid * 16;
      int row = off >> 7, colb = off & 127;
      gload16((const char*)g.Bt + (size_t)(n0 + row) * 2048 + (k0 << 1) + colb,
              (char*)lB + i * 4096 + wave * 1024);
    }
    __syncthreads();
#pragma unroll
    for (int kk = 0; kk < 2; ++kk) {
      bf16x8 af[MT], bfr[NT];
#pragma unroll
      for (int mt = 0; mt < MT; ++mt) {
        int row = wr * (BM / WR) + mt * 16 + lo;
        int ob = (row << 7) + ((((kk << 2) + hi) << 4) ^ ((row & 7) << 4));
        af[mt] = *(const bf16x8*)((const char*)lA + ob);
      }
#pragma unroll
      for (int nt = 0; nt < NT; ++nt) {
        int row = wc * (BN / WC) + nt * 16 + lo;
        int ob = (row << 7) + ((((kk << 2) + hi) << 4) ^ ((row & 7) << 4));
        bfr[nt] = *(const bf16x8*)((const char*)lB + ob);
      }
#pragma unroll
      for (int mt = 0; mt < MT; ++mt)
#pragma unroll
        for (int nt = 0; nt < NT; ++nt)
          acc[mt][nt] = mfma16(af[mt], bfr[nt], acc[mt][nt]);
    }
    __syncthreads();
  }
#pragma unroll
  for (int mt = 0; mt < MT; ++mt) {
#pragma unroll
    for (int nt = 0; nt < NT; ++nt) {
      int col = n0 + wc * (BN / WC) + nt * 16 + lo;
      float bs = g.bias[col];
#pragma unroll
      for (int j = 0; j < 4; ++j) {
        int row = m0 + wr * (BM / WR) + mt * 16 + (hi << 2) + j;
        float v = (acc[mt][nt][j] + bs) * g.scale;
        if (MODE == 1) {
          g.outF[(size_t)row * 1024 + col] = v;
        } else {
          size_t hb = ((size_t)((row >> 11) * 16 + (col >> 6))) << 18;
          int ib = ((row & 2047) << 7) + ((col & 63) << 1);
          ib ^= (row & 7) << 4;
          *(__bf16*)((char*)g.outH + hb + ib) = (__bf16)v;
        }
      }
    }
  }
}

// ---------------------------------------------------------------------------
// Transpose V head-layout (B,H,S,64) swizzled -> (B,H,64,S) swizzled
// ---------------------------------------------------------------------------
__global__ __launch_bounds__(256) void transV(const unsigned short* __restrict__ vh,
                                              unsigned short* __restrict__ vt) {
  __shared__ unsigned short t[64][72];
  int k0 = blockIdx.x * 64;
  int bh = blockIdx.y;
  int tid = threadIdx.x;
  const char* head = (const char*)vh + ((size_t)bh << 18);
#pragma unroll
  for (int it = 0; it < 2; ++it) {
    int off = it * 4096 + tid * 16;
    int r = off >> 7, cb = off & 127;
    u16x8 v = *(const u16x8*)(head + (size_t)(k0 + r) * 128 + (cb ^ ((r & 7) << 4)));
    *(u16x8*)&t[r][cb >> 1] = v;
  }
  __syncthreads();
  char* ohead = (char*)vt + ((size_t)bh << 18);
#pragma unroll
  for (int it = 0; it < 2; ++it) {
    int d = it * 32 + (tid >> 3);
    int kc = tid & 7;
    u16x8 o;
#pragma unroll
    for (int j = 0; j < 8; ++j) o[j] = t[kc * 8 + j][d];
    *(u16x8*)(ohead + (size_t)d * 4096 + (k0 << 1) + ((kc ^ (d & 7)) << 4)) = o;
  }
}

// ---------------------------------------------------------------------------
// Fused attention. Change vs R2: pass-2 stages the wave's 16x64 normalized
// P-tile in LDS fp32 (stride 68), then stores attention as 4x dwordx4 nt
// stores per lane (1KB/instr) and feeds PV from the same tile (bf16 cvt).
// Accumulator is pre-normalized -> no rcp at the end.
// ---------------------------------------------------------------------------
__global__ __launch_bounds__(256, 2) void attn_k(
    const unsigned short* __restrict__ qh, const unsigned short* __restrict__ kh,
    const unsigned short* __restrict__ vt, const int* __restrict__ mask,
    float* __restrict__ attn, unsigned short* __restrict__ ctx) {
  constexpr int S = 2048;
  __shared__ unsigned short ktl[64 * 64];
  __shared__ unsigned short vtl[64 * 64];
  __shared__ unsigned long long mkb[32];
  __shared__ float pf[4][16 * 68];

  int tid = threadIdx.x, wave = tid >> 6, lane = tid & 63;
  int hi = lane >> 4, lo = lane & 15;
  int f = blockIdx.y * 32 + blockIdx.x;
  int xcd = f & 7, slot = f >> 3;
  int bh = xcd * 4 + (slot & 3);
  int qb = slot >> 2;
  int b = bh >> 4, h = bh & 15;
  const char* khead = (const char*)kh + ((size_t)bh << 18);
  const char* qhead = (const char*)qh + ((size_t)bh << 18);
  const char* vhead = (const char*)vt + ((size_t)bh << 18);

  for (int it = 0; it < 8; ++it) {
    unsigned long long bal = __ballot(mask[b * S + it * 256 + tid] != 0);
    if (lane == 0) mkb[it * 4 + wave] = bal;
  }
  __syncthreads();

  int q0 = qb * 64 + wave * 16;
  bf16x8 qf[2];
  {
    int row = q0 + lo;
#pragma unroll
    for (int kk = 0; kk < 2; ++kk) {
      int ib = (row << 7) + ((((kk << 2) + hi) << 4) ^ ((row & 7) << 4));
      qf[kk] = *(const bf16x8*)(qhead + ib);
    }
  }

  float lsum[4] = {0.f, 0.f, 0.f, 0.f};

  // ---- pass 1: row sums ----
  for (int kt = 0; kt < 32; ++kt) {
#pragma unroll
    for (int i = 0; i < 2; ++i)
      gload16(khead + (size_t)kt * 8192 + i * 4096 + tid * 16,
              (char*)ktl + i * 4096 + wave * 1024);
    __syncthreads();
    unsigned long long mw = mkb[kt];
#pragma unroll
    for (int nt = 0; nt < 4; ++nt) {
      int r = nt * 16 + lo;
      f32x4 a = {0.f, 0.f, 0.f, 0.f};
#pragma unroll
      for (int kk = 0; kk < 2; ++kk) {
        int ob = (r << 7) + ((((kk << 2) + hi) << 4) ^ ((r & 7) << 4));
        a = mfma16(qf[kk], *(const bf16x8*)((const char*)ktl + ob), a);
      }
      bool ok = (mw >> r) & 1ull;
#pragma unroll
      for (int j = 0; j < 4; ++j) lsum[j] += ok ? EXP2(a[j]) : 0.f;
    }
    __syncthreads();
  }

  float rcp[4];
#pragma unroll
  for (int j = 0; j < 4; ++j) {
    float s = lsum[j];
    s += __shfl_xor(s, 1); s += __shfl_xor(s, 2);
    s += __shfl_xor(s, 4); s += __shfl_xor(s, 8);
    rcp[j] = s > 0.f ? 1.0f / s : 0.f;
  }

  f32x4 cacc[4];
#pragma unroll
  for (int nt = 0; nt < 4; ++nt) cacc[nt] = (f32x4){0.f, 0.f, 0.f, 0.f};

  float* arow = attn + (size_t)bh * S * S;
  float* pfw = pf[wave];

  // ---- pass 2: recompute, stage P in LDS, vector-store attn, PV ----
  for (int kt = 0; kt < 32; ++kt) {
#pragma unroll
    for (int i = 0; i < 2; ++i)
      gload16(khead + (size_t)kt * 8192 + i * 4096 + tid * 16,
              (char*)ktl + i * 4096 + wave * 1024);
#pragma unroll
    for (int i = 0; i < 2; ++i) {
      int off = i * 4096 + tid * 16;
      int d = off >> 7, x = off & 127;
      gload16(vhead + (size_t)d * 4096 + kt * 128 + x,
              (char*)vtl + i * 4096 + wave * 1024);
    }
    __syncthreads();
    unsigned long long mw = mkb[kt];
#pragma unroll
    for (int nt = 0; nt < 4; ++nt) {
      int r = nt * 16 + lo;
      f32x4 a = {0.f, 0.f, 0.f, 0.f};
#pragma unroll
      for (int kk = 0; kk < 2; ++kk) {
        int ob = (r << 7) + ((((kk << 2) + hi) << 4) ^ ((r & 7) << 4));
        a = mfma16(qf[kk], *(const bf16x8*)((const char*)ktl + ob), a);
      }
      bool ok = (mw >> r) & 1ull;
#pragma unroll
      for (int j = 0; j < 4; ++j) {
        float pn = ok ? EXP2(a[j]) * rcp[j] : 0.f;
        pfw[((hi << 2) + j) * 68 + r] = pn;  // normalized P tile
      }
    }
    // same-wave DS ordering: compiler inserts lgkmcnt before dependent reads
    // PV: read normalized P back as bf16 fragments
#pragma unroll
    for (int c = 0; c < 2; ++c) {
      f32x4 p0 = *(const f32x4*)&pfw[lo * 68 + c * 32 + hi * 8];
      f32x4 p1 = *(const f32x4*)&pfw[lo * 68 + c * 32 + hi * 8 + 4];
      bf16x8 pa;
#pragma unroll
      for (int i = 0; i < 4; ++i) { pa[i] = (__bf16)p0[i]; pa[4 + i] = (__bf16)p1[i]; }
#pragma unroll
      for (int nt = 0; nt < 4; ++nt) {
        int d = nt * 16 + lo;
        int ob = (d << 7) + ((((c << 2) + hi) << 4) ^ ((d & 7) << 4));
        cacc[nt] = mfma16(pa, *(const bf16x8*)((const char*)vtl + ob), cacc[nt]);
      }
    }
    // attention store: 4 x dwordx4 nontemporal per lane, 16 rows x 64B/instr
    {
      int r2 = lane >> 2;
      int cb0 = (lane & 3) << 2;
      float* dst = arow + (size_t)(q0 + r2) * S + kt * 64;
      const float* srcr = pfw + r2 * 68;
#pragma unroll
      for (int s = 0; s < 4; ++s) {
        int cb = cb0 + (s << 4);
        f32x4 v = *(const f32x4*)&srcr[cb];
        __builtin_nontemporal_store(v, (f32x4*)(dst + cb));
      }
    }
    __syncthreads();
  }

  // context write, layout (B,S,1024) row-swizzled bf16 (already normalized)
#pragma unroll
  for (int nt = 0; nt < 4; ++nt) {
#pragma unroll
    for (int j = 0; j < 4; ++j) {
      int s = q0 + (hi << 2) + j;
      int mrow = b * S + s;
      int n = h * 64 + nt * 16 + lo;
      int ib = (n << 1) ^ ((mrow & 7) << 4);
      *(__bf16*)((char*)ctx + (size_t)mrow * 2048 + ib) = (__bf16)cacc[nt][j];
    }
  }
}

// ---------------------------------------------------------------------------
extern "C" void kernel_launch(void* const* d_in, const int* in_sizes, int n_in,
                              void* d_out, int out_size, void* d_ws, size_t ws_size,
                              hipStream_t stream) {
  const float* Q  = (const float*)d_in[0];
  const float* K  = (const float*)d_in[1];
  const float* V  = (const float*)d_in[2];
  const int* mask = (const int*)d_in[3];
  const float* WQ = (const float*)d_in[4];
  const float* bQ = (const float*)d_in[5];
  const float* WK = (const float*)d_in[6];
  const float* bK = (const float*)d_in[7];
  const float* WV = (const float*)d_in[8];
  const float* bV = (const float*)d_in[9];
  const float* WO = (const float*)d_in[10];
  const float* bO = (const float*)d_in[11];

  char* ws = (char*)d_ws;
  const size_t M1 = 1ull << 20;
  unsigned short* WQt = (unsigned short*)(ws + 0 * M1);
  unsigned short* WKt = (unsigned short*)(ws + 2 * M1);
  unsigned short* WVt = (unsigned short*)(ws + 4 * M1);
  unsigned short* WOt = (unsigned short*)(ws + 6 * M1);
  unsigned short* qh  = (unsigned short*)(ws + 8 * M1);
  unsigned short* kh  = (unsigned short*)(ws + 16 * M1);
  unsigned short* vh  = (unsigned short*)(ws + 24 * M1);
  unsigned short* Qb  = (unsigned short*)(ws + 32 * M1);
  unsigned short* Kb  = (unsigned short*)(ws + 40 * M1);
  unsigned short* Vb  = (unsigned short*)(ws + 32 * M1);  // after gemmQK (Qb dead)
  unsigned short* vt  = (unsigned short*)(ws + 40 * M1);  // after gemmQK (Kb dead)
  unsigned short* ctx = (unsigned short*)(ws + 32 * M1);  // after gemmV (Vb dead)

  float* outF = (float*)d_out;                 // (B,S,1024) fp32
  float* attn = (float*)d_out + 4194304;       // (B,H,S,S) fp32

  dim3 blk(256);
  const float qscale = 0.125f * 1.44269504088896340736f;

  cvt2_k<<<dim3(2048, 1, 2), blk, 0, stream>>>(Q, Qb, K, Kb);
  transW4<<<dim3(16, 16, 4), blk, 0, stream>>>(WQ, WK, WV, WO, WQt);

  GArg aq{Qb, WQt, bQ, qh, nullptr, qscale};
  GArg ak{Kb, WKt, bK, kh, nullptr, 1.f};
  gemm_t<128, 128, 2, 2, 0><<<dim3(32, 8, 2), blk, 0, stream>>>(aq, ak);

  cvt2_k<<<dim3(2048, 1, 1), blk, 0, stream>>>(V, Vb, V, Vb);

  GArg av{Vb, WVt, bV, vh, nullptr, 1.f};
  gemm_t<64, 128, 1, 4, 0><<<dim3(64, 8, 1), blk, 0, stream>>>(av, av);

  transV<<<dim3(32, 32), blk, 0, stream>>>(vh, vt);

  attn_k<<<dim3(32, 32), blk, 0, stream>>>(qh, kh, vt, mask, attn, ctx);

  GArg ao{ctx, WOt, bO, nullptr, outF, 1.f};
  gemm_t<64, 128, 1, 4, 1><<<dim3(64, 8, 1), blk, 0, stream>>>(ao, ao);
}

// Round 4
// 257.149 us; speedup vs baseline: 1.3840x; 1.3287x over previous
//
#include <hip/hip_runtime.h>

typedef __attribute__((ext_vector_type(8))) __bf16 bf16x8;
typedef __attribute__((ext_vector_type(4))) float f32x4;
typedef __attribute__((ext_vector_type(8))) unsigned short u16x8;

#define DEVFN static __device__ __forceinline__

#if __has_builtin(__builtin_amdgcn_exp2f)
#define EXP2(x) __builtin_amdgcn_exp2f(x)
#else
#define EXP2(x) exp2f(x)
#endif

DEVFN f32x4 mfma16(bf16x8 a, bf16x8 b, f32x4 c) {
  return __builtin_amdgcn_mfma_f32_16x16x32_bf16(a, b, c, 0, 0, 0);
}

DEVFN void gload16(const void* g, void* l) {
  __builtin_amdgcn_global_load_lds((const __attribute__((address_space(1))) void*)g,
                                   (__attribute__((address_space(3))) void*)l, 16, 0, 0);
}

// ---------------------------------------------------------------------------
// fp32 [R][1024] -> bf16 row-swizzled (byte ^= (row&7)<<4 within 128B blocks)
// ---------------------------------------------------------------------------
__global__ __launch_bounds__(256) void cvt2_k(const float* __restrict__ s0,
                                              unsigned short* __restrict__ d0,
                                              const float* __restrict__ s1,
                                              unsigned short* __restrict__ d1) {
  const float* in = blockIdx.z ? s1 : s0;
  unsigned short* out = blockIdx.z ? d1 : d0;
  int i = blockIdx.x * 256 + threadIdx.x;
  int e0 = i << 3;
  int row = e0 >> 10, col0 = e0 & 1023;
  const float4* s = (const float4*)(in + ((size_t)row << 10) + col0);
  float4 a = s[0], b = s[1];
  bf16x8 o;
  o[0] = (__bf16)a.x; o[1] = (__bf16)a.y; o[2] = (__bf16)a.z; o[3] = (__bf16)a.w;
  o[4] = (__bf16)b.x; o[5] = (__bf16)b.y; o[6] = (__bf16)b.z; o[7] = (__bf16)b.w;
  size_t ob = ((size_t)row << 11) + (size_t)((col0 << 1) ^ ((row & 7) << 4));
  *(bf16x8*)((char*)out + ob) = o;
}

// ---------------------------------------------------------------------------
// Transpose+convert weights: W fp32 [1024 k][1024 n] -> Wt bf16 [n][k] swizzled
// ---------------------------------------------------------------------------
__global__ __launch_bounds__(256) void transW4(const float* __restrict__ w0,
                                               const float* __restrict__ w1,
                                               const float* __restrict__ w2,
                                               const float* __restrict__ w3,
                                               unsigned short* __restrict__ obase) {
  __shared__ float t[64][65];
  const float* W = blockIdx.z == 0 ? w0 : blockIdx.z == 1 ? w1 : blockIdx.z == 2 ? w2 : w3;
  unsigned short* Wt = obase + ((size_t)blockIdx.z << 20);
  int k0 = blockIdx.x * 64, n0 = blockIdx.y * 64;
  int tid = threadIdx.x;
#pragma unroll
  for (int it = 0; it < 4; ++it) {
    int r = it * 16 + (tid >> 4);
    int c = (tid & 15) * 4;
    float4 v = *(const float4*)(W + (size_t)(k0 + r) * 1024 + n0 + c);
    t[r][c] = v.x; t[r][c + 1] = v.y; t[r][c + 2] = v.z; t[r][c + 3] = v.w;
  }
  __syncthreads();
#pragma unroll
  for (int it = 0; it < 2; ++it) {
    int nl = it * 32 + (tid >> 3);
    int kc = tid & 7;
    bf16x8 o;
#pragma unroll
    for (int j = 0; j < 8; ++j) o[j] = (__bf16)t[kc * 8 + j][nl];
    int n = n0 + nl;
    char* dst = (char*)Wt + (size_t)n * 2048 + (k0 << 1) + ((kc ^ (n & 7)) << 4);
    *(bf16x8*)dst = o;
  }
}

// ---------------------------------------------------------------------------
// Templated GEMM (unchanged)
// ---------------------------------------------------------------------------
struct GArg {
  const unsigned short* A;
  const unsigned short* Bt;
  const float* bias;
  unsigned short* outH;
  float* outF;
  float scale;
};

template <int BM, int BN, int WR, int WC, int MODE>
__global__ __launch_bounds__(256, 2) void gemm_t(GArg g0, GArg g1) {
  GArg g = (blockIdx.z == 0) ? g0 : g1;
  constexpr int MT = BM / WR / 16, NT = BN / WC / 16;
  __shared__ unsigned short lA[BM * 64];
  __shared__ unsigned short lB[BN * 64];
  int tid = threadIdx.x, wave = tid >> 6, lane = tid & 63;
  int hi = lane >> 4, lo = lane & 15;
  int m0 = blockIdx.x * BM, n0 = blockIdx.y * BN;
  int wr = wave / WC, wc = wave % WC;
  f32x4 acc[MT][NT];
#pragma unroll
  for (int mt = 0; mt < MT; ++mt)
#pragma unroll
    for (int nt = 0; nt < NT; ++nt) acc[mt][nt] = (f32x4){0.f, 0.f, 0.f, 0.f};

  for (int k0 = 0; k0 < 1024; k0 += 64) {
#pragma unroll
    for (int i = 0; i < BM / 32; ++i) {
      int off = i * 4096 + tid * 16;
      int row = off >> 7, colb = off & 127;
      gload16((const char*)g.A + (size_t)(m0 + row) * 2048 + (k0 << 1) + colb,
              (char*)lA + i * 4096 + wave * 1024);
    }
#pragma unroll
    for (int i = 0; i < BN / 32; ++i) {
      int off = i * 4096 + tid * 16;
      int row = off >> 7, colb = off & 127;
      gload16((const char*)g.Bt + (size_t)(n0 + row) * 2048 + (k0 << 1) + colb,
              (char*)lB + i * 4096 + wave * 1024);
    }
    __syncthreads();
#pragma unroll
    for (int kk = 0; kk < 2; ++kk) {
      bf16x8 af[MT], bfr[NT];
#pragma unroll
      for (int mt = 0; mt < MT; ++mt) {
        int row = wr * (BM / WR) + mt * 16 + lo;
        int ob = (row << 7) + ((((kk << 2) + hi) << 4) ^ ((row & 7) << 4));
        af[mt] = *(const bf16x8*)((const char*)lA + ob);
      }
#pragma unroll
      for (int nt = 0; nt < NT; ++nt) {
        int row = wc * (BN / WC) + nt * 16 + lo;
        int ob = (row << 7) + ((((kk << 2) + hi) << 4) ^ ((row & 7) << 4));
        bfr[nt] = *(const bf16x8*)((const char*)lB + ob);
      }
#pragma unroll
      for (int mt = 0; mt < MT; ++mt)
#pragma unroll
        for (int nt = 0; nt < NT; ++nt)
          acc[mt][nt] = mfma16(af[mt], bfr[nt], acc[mt][nt]);
    }
    __syncthreads();
  }
#pragma unroll
  for (int mt = 0; mt < MT; ++mt) {
#pragma unroll
    for (int nt = 0; nt < NT; ++nt) {
      int col = n0 + wc * (BN / WC) + nt * 16 + lo;
      float bs = g.bias[col];
#pragma unroll
      for (int j = 0; j < 4; ++j) {
        int row = m0 + wr * (BM / WR) + mt * 16 + (hi << 2) + j;
        float v = (acc[mt][nt][j] + bs) * g.scale;
        if (MODE == 1) {
          g.outF[(size_t)row * 1024 + col] = v;
        } else {
          size_t hb = ((size_t)((row >> 11) * 16 + (col >> 6))) << 18;
          int ib = ((row & 2047) << 7) + ((col & 63) << 1);
          ib ^= (row & 7) << 4;
          *(__bf16*)((char*)g.outH + hb + ib) = (__bf16)v;
        }
      }
    }
  }
}

// ---------------------------------------------------------------------------
// Transpose V head-layout (B,H,S,64) swizzled -> (B,H,64,S) swizzled
// ---------------------------------------------------------------------------
__global__ __launch_bounds__(256) void transV(const unsigned short* __restrict__ vh,
                                              unsigned short* __restrict__ vt) {
  __shared__ unsigned short t[64][72];
  int k0 = blockIdx.x * 64;
  int bh = blockIdx.y;
  int tid = threadIdx.x;
  const char* head = (const char*)vh + ((size_t)bh << 18);
#pragma unroll
  for (int it = 0; it < 2; ++it) {
    int off = it * 4096 + tid * 16;
    int r = off >> 7, cb = off & 127;
    u16x8 v = *(const u16x8*)(head + (size_t)(k0 + r) * 128 + (cb ^ ((r & 7) << 4)));
    *(u16x8*)&t[r][cb >> 1] = v;
  }
  __syncthreads();
  char* ohead = (char*)vt + ((size_t)bh << 18);
#pragma unroll
  for (int it = 0; it < 2; ++it) {
    int d = it * 32 + (tid >> 3);
    int kc = tid & 7;
    u16x8 o;
#pragma unroll
    for (int j = 0; j < 8; ++j) o[j] = t[kc * 8 + j][d];
    *(u16x8*)(ohead + (size_t)d * 4096 + (k0 << 1) + ((kc ^ (d & 7)) << 4)) = o;
  }
}

// ---------------------------------------------------------------------------
// Fused attention. R4 changes: 4 blocks/CU occupancy, 256B-contiguous attn
// stores (4 rows x 256B per dwordx4 instr), setprio around MFMA clusters.
// ---------------------------------------------------------------------------
__global__ __launch_bounds__(256, 4) void attn_k(
    const unsigned short* __restrict__ qh, const unsigned short* __restrict__ kh,
    const unsigned short* __restrict__ vt, const int* __restrict__ mask,
    float* __restrict__ attn, unsigned short* __restrict__ ctx) {
  constexpr int S = 2048;
  __shared__ unsigned short ktl[64 * 64];
  __shared__ unsigned short vtl[64 * 64];
  __shared__ unsigned long long mkb[32];
  __shared__ float pf[4][16 * 68];

  int tid = threadIdx.x, wave = tid >> 6, lane = tid & 63;
  int hi = lane >> 4, lo = lane & 15;
  int f = blockIdx.y * 32 + blockIdx.x;
  int xcd = f & 7, slot = f >> 3;
  int bh = xcd * 4 + (slot & 3);
  int qb = slot >> 2;
  int b = bh >> 4, h = bh & 15;
  const char* khead = (const char*)kh + ((size_t)bh << 18);
  const char* qhead = (const char*)qh + ((size_t)bh << 18);
  const char* vhead = (const char*)vt + ((size_t)bh << 18);

  for (int it = 0; it < 8; ++it) {
    unsigned long long bal = __ballot(mask[b * S + it * 256 + tid] != 0);
    if (lane == 0) mkb[it * 4 + wave] = bal;
  }
  __syncthreads();

  int q0 = qb * 64 + wave * 16;
  bf16x8 qf[2];
  {
    int row = q0 + lo;
#pragma unroll
    for (int kk = 0; kk < 2; ++kk) {
      int ib = (row << 7) + ((((kk << 2) + hi) << 4) ^ ((row & 7) << 4));
      qf[kk] = *(const bf16x8*)(qhead + ib);
    }
  }

  float lsum[4] = {0.f, 0.f, 0.f, 0.f};

  // ---- pass 1: row sums ----
  for (int kt = 0; kt < 32; ++kt) {
#pragma unroll
    for (int i = 0; i < 2; ++i)
      gload16(khead + (size_t)kt * 8192 + i * 4096 + tid * 16,
              (char*)ktl + i * 4096 + wave * 1024);
    __syncthreads();
    unsigned long long mw = mkb[kt];
    __builtin_amdgcn_s_setprio(1);
#pragma unroll
    for (int nt = 0; nt < 4; ++nt) {
      int r = nt * 16 + lo;
      f32x4 a = {0.f, 0.f, 0.f, 0.f};
#pragma unroll
      for (int kk = 0; kk < 2; ++kk) {
        int ob = (r << 7) + ((((kk << 2) + hi) << 4) ^ ((r & 7) << 4));
        a = mfma16(qf[kk], *(const bf16x8*)((const char*)ktl + ob), a);
      }
      bool ok = (mw >> r) & 1ull;
#pragma unroll
      for (int j = 0; j < 4; ++j) lsum[j] += ok ? EXP2(a[j]) : 0.f;
    }
    __builtin_amdgcn_s_setprio(0);
    __syncthreads();
  }

  float rcp[4];
#pragma unroll
  for (int j = 0; j < 4; ++j) {
    float s = lsum[j];
    s += __shfl_xor(s, 1); s += __shfl_xor(s, 2);
    s += __shfl_xor(s, 4); s += __shfl_xor(s, 8);
    rcp[j] = s > 0.f ? 1.0f / s : 0.f;
  }

  f32x4 cacc[4];
#pragma unroll
  for (int nt = 0; nt < 4; ++nt) cacc[nt] = (f32x4){0.f, 0.f, 0.f, 0.f};

  float* arow = attn + (size_t)bh * S * S;
  float* pfw = pf[wave];

  // ---- pass 2: recompute, stage P in LDS, vector-store attn, PV ----
  for (int kt = 0; kt < 32; ++kt) {
#pragma unroll
    for (int i = 0; i < 2; ++i)
      gload16(khead + (size_t)kt * 8192 + i * 4096 + tid * 16,
              (char*)ktl + i * 4096 + wave * 1024);
#pragma unroll
    for (int i = 0; i < 2; ++i) {
      int off = i * 4096 + tid * 16;
      int d = off >> 7, x = off & 127;
      gload16(vhead + (size_t)d * 4096 + kt * 128 + x,
              (char*)vtl + i * 4096 + wave * 1024);
    }
    __syncthreads();
    unsigned long long mw = mkb[kt];
    __builtin_amdgcn_s_setprio(1);
#pragma unroll
    for (int nt = 0; nt < 4; ++nt) {
      int r = nt * 16 + lo;
      f32x4 a = {0.f, 0.f, 0.f, 0.f};
#pragma unroll
      for (int kk = 0; kk < 2; ++kk) {
        int ob = (r << 7) + ((((kk << 2) + hi) << 4) ^ ((r & 7) << 4));
        a = mfma16(qf[kk], *(const bf16x8*)((const char*)ktl + ob), a);
      }
      bool ok = (mw >> r) & 1ull;
#pragma unroll
      for (int j = 0; j < 4; ++j) {
        float pn = ok ? EXP2(a[j]) * rcp[j] : 0.f;
        pfw[((hi << 2) + j) * 68 + r] = pn;  // normalized P tile
      }
    }
    // PV: read normalized P back as bf16 fragments (same-wave DS ordering)
#pragma unroll
    for (int c = 0; c < 2; ++c) {
      f32x4 p0 = *(const f32x4*)&pfw[lo * 68 + c * 32 + hi * 8];
      f32x4 p1 = *(const f32x4*)&pfw[lo * 68 + c * 32 + hi * 8 + 4];
      bf16x8 pa;
#pragma unroll
      for (int i = 0; i < 4; ++i) { pa[i] = (__bf16)p0[i]; pa[4 + i] = (__bf16)p1[i]; }
#pragma unroll
      for (int nt = 0; nt < 4; ++nt) {
        int d = nt * 16 + lo;
        int ob = (d << 7) + ((((c << 2) + hi) << 4) ^ ((d & 7) << 4));
        cacc[nt] = mfma16(pa, *(const bf16x8*)((const char*)vtl + ob), cacc[nt]);
      }
    }
    __builtin_amdgcn_s_setprio(0);
    // attention store: 4 rows x 256B contiguous per dwordx4 instruction
    {
      int rsub = lane >> 4;        // 0..3
      int cb = (lane & 15) << 2;   // 0..60, 16B steps
      float* dst0 = arow + (size_t)q0 * S + kt * 64 + cb;
      const float* src0 = pfw + rsub * 68 + cb;
#pragma unroll
      for (int s = 0; s < 4; ++s) {
        int row = s * 4 + rsub;
        f32x4 v = *(const f32x4*)(src0 + s * 4 * 68);
        __builtin_nontemporal_store(v, (f32x4*)(dst0 + (size_t)row * S - (size_t)rsub * S + (size_t)rsub * S));
      }
    }
    __syncthreads();
  }

  // context write, layout (B,S,1024) row-swizzled bf16 (already normalized)
#pragma unroll
  for (int nt = 0; nt < 4; ++nt) {
#pragma unroll
    for (int j = 0; j < 4; ++j) {
      int s = q0 + (hi << 2) + j;
      int mrow = b * S + s;
      int n = h * 64 + nt * 16 + lo;
      int ib = (n << 1) ^ ((mrow & 7) << 4);
      *(__bf16*)((char*)ctx + (size_t)mrow * 2048 + ib) = (__bf16)cacc[nt][j];
    }
  }
}

// ---------------------------------------------------------------------------
extern "C" void kernel_launch(void* const* d_in, const int* in_sizes, int n_in,
                              void* d_out, int out_size, void* d_ws, size_t ws_size,
                              hipStream_t stream) {
  const float* Q  = (const float*)d_in[0];
  const float* K  = (const float*)d_in[1];
  const float* V  = (const float*)d_in[2];
  const int* mask = (const int*)d_in[3];
  const float* WQ = (const float*)d_in[4];
  const float* bQ = (const float*)d_in[5];
  const float* WK = (const float*)d_in[6];
  const float* bK = (const float*)d_in[7];
  const float* WV = (const float*)d_in[8];
  const float* bV = (const float*)d_in[9];
  const float* WO = (const float*)d_in[10];
  const float* bO = (const float*)d_in[11];

  char* ws = (char*)d_ws;
  const size_t M1 = 1ull << 20;
  unsigned short* WQt = (unsigned short*)(ws + 0 * M1);
  unsigned short* WKt = (unsigned short*)(ws + 2 * M1);
  unsigned short* WVt = (unsigned short*)(ws + 4 * M1);
  unsigned short* WOt = (unsigned short*)(ws + 6 * M1);
  unsigned short* qh  = (unsigned short*)(ws + 8 * M1);
  unsigned short* kh  = (unsigned short*)(ws + 16 * M1);
  unsigned short* vh  = (unsigned short*)(ws + 24 * M1);
  unsigned short* Qb  = (unsigned short*)(ws + 32 * M1);
  unsigned short* Kb  = (unsigned short*)(ws + 40 * M1);
  unsigned short* Vb  = (unsigned short*)(ws + 32 * M1);
  unsigned short* vt  = (unsigned short*)(ws + 40 * M1);
  unsigned short* ctx = (unsigned short*)(ws + 32 * M1);

  float* outF = (float*)d_out;                 // (B,S,1024) fp32
  float* attn = (float*)d_out + 4194304;       // (B,H,S,S) fp32

  dim3 blk(256);
  const float qscale = 0.125f * 1.44269504088896340736f;

  cvt2_k<<<dim3(2048, 1, 2), blk, 0, stream>>>(Q, Qb, K, Kb);
  transW4<<<dim3(16, 16, 4), blk, 0, stream>>>(WQ, WK, WV, WO, WQt);

  GArg aq{Qb, WQt, bQ, qh, nullptr, qscale};
  GArg ak{Kb, WKt, bK, kh, nullptr, 1.f};
  gemm_t<128, 128, 2, 2, 0><<<dim3(32, 8, 2), blk, 0, stream>>>(aq, ak);

  cvt2_k<<<dim3(2048, 1, 1), blk, 0, stream>>>(V, Vb, V, Vb);

  GArg av{Vb, WVt, bV, vh, nullptr, 1.f};
  gemm_t<64, 128, 1, 4, 0><<<dim3(64, 8, 1), blk, 0, stream>>>(av, av);

  transV<<<dim3(32, 32), blk, 0, stream>>>(vh, vt);

  attn_k<<<dim3(32, 32), blk, 0, stream>>>(qh, kh, vt, mask, attn, ctx);

  GArg ao{ctx, WOt, bO, nullptr, outF, 1.f};
  gemm_t<64, 128, 1, 4, 1><<<dim3(64, 8, 1), blk, 0, stream>>>(ao, ao);
}

// Round 5
// 246.448 us; speedup vs baseline: 1.4441x; 1.0434x over previous
//
#include <hip/hip_runtime.h>

typedef __attribute__((ext_vector_type(8))) __bf16 bf16x8;
typedef __attribute__((ext_vector_type(4))) __bf16 bf16x4;
typedef __attribute__((ext_vector_type(4))) float f32x4;

#define DEVFN static __device__ __forceinline__

#if __has_builtin(__builtin_amdgcn_exp2f)
#define EXP2(x) __builtin_amdgcn_exp2f(x)
#else
#define EXP2(x) exp2f(x)
#endif

DEVFN f32x4 mfma16(bf16x8 a, bf16x8 b, f32x4 c) {
  return __builtin_amdgcn_mfma_f32_16x16x32_bf16(a, b, c, 0, 0, 0);
}

DEVFN void gload16(const void* g, void* l) {
  __builtin_amdgcn_global_load_lds((const __attribute__((address_space(1))) void*)g,
                                   (__attribute__((address_space(3))) void*)l, 16, 0, 0);
}

// ---------------------------------------------------------------------------
// Transpose+convert weights: W fp32 [1024 k][1024 n] -> Wt bf16 [n][k] swizzled
// (byte-in-row: 16B-unit index XOR'd by n&7 within each 128B block)
// ---------------------------------------------------------------------------
__global__ __launch_bounds__(256) void transW4(const float* __restrict__ w0,
                                               const float* __restrict__ w1,
                                               const float* __restrict__ w2,
                                               const float* __restrict__ w3,
                                               unsigned short* __restrict__ obase) {
  __shared__ float t[64][65];
  const float* W = blockIdx.z == 0 ? w0 : blockIdx.z == 1 ? w1 : blockIdx.z == 2 ? w2 : w3;
  unsigned short* Wt = obase + ((size_t)blockIdx.z << 20);
  int k0 = blockIdx.x * 64, n0 = blockIdx.y * 64;
  int tid = threadIdx.x;
#pragma unroll
  for (int it = 0; it < 4; ++it) {
    int r = it * 16 + (tid >> 4);
    int c = (tid & 15) * 4;
    float4 v = *(const float4*)(W + (size_t)(k0 + r) * 1024 + n0 + c);
    t[r][c] = v.x; t[r][c + 1] = v.y; t[r][c + 2] = v.z; t[r][c + 3] = v.w;
  }
  __syncthreads();
#pragma unroll
  for (int it = 0; it < 2; ++it) {
    int nl = it * 32 + (tid >> 3);
    int kc = tid & 7;
    bf16x8 o;
#pragma unroll
    for (int j = 0; j < 8; ++j) o[j] = (__bf16)t[kc * 8 + j][nl];
    int n = n0 + nl;
    char* dst = (char*)Wt + (size_t)n * 2048 + (k0 << 1) + ((kc ^ (n & 7)) << 4);
    *(bf16x8*)dst = o;
  }
}

// ---------------------------------------------------------------------------
// GEMM C = A[4096x1024] * Bt[1024x1024]^T (+bias)*scale
// AF32=1: A is raw fp32 row-major (pre-swizzled global src, bf16 cvt after
//         ds_read).  AF32=0: A is bf16 row-swizzled (ctx path).
// EPI=0: z<2 -> bf16 head layout (B,H,S,64) swizzled; z==2 -> vt transposed
//        (B,H,64,S) swizzled.  EPI=1: fp32 row-major.
// ---------------------------------------------------------------------------
struct GArg {
  const void* A;
  const unsigned short* Bt;
  const float* bias;
  void* out;
  float scale;
};

template <int BM, int BN, int WR, int WC, int AF32, int EPI>
__global__ __launch_bounds__(256, 2) void gemm_t(GArg g0, GArg g1, GArg g2) {
  GArg g = blockIdx.z == 0 ? g0 : blockIdx.z == 1 ? g1 : g2;
  constexpr int MT = BM / WR / 16, NT = BN / WC / 16;
  constexpr int AB = AF32 ? 4 : 2;
  __shared__ char lA[BM * 64 * AB];
  __shared__ char lB[BN * 64 * 2];
  int tid = threadIdx.x, wave = tid >> 6, lane = tid & 63;
  int hi = lane >> 4, lo = lane & 15;
  int m0 = blockIdx.x * BM, n0 = blockIdx.y * BN;
  int wr = wave / WC, wc = wave % WC;
  f32x4 acc[MT][NT];
#pragma unroll
  for (int mt = 0; mt < MT; ++mt)
#pragma unroll
    for (int nt = 0; nt < NT; ++nt) acc[mt][nt] = (f32x4){0.f, 0.f, 0.f, 0.f};

  for (int k0 = 0; k0 < 1024; k0 += 64) {
    if (AF32) {
#pragma unroll
      for (int i = 0; i < BM / 16; ++i) {
        int off = i * 4096 + tid * 16;
        int row = off >> 8, b = off & 255;
        gload16((const char*)g.A + (size_t)(m0 + row) * 4096 + (k0 << 2)
                    + (b ^ ((row & 7) << 4)),
                lA + i * 4096 + wave * 1024);
      }
    } else {
#pragma unroll
      for (int i = 0; i < BM / 32; ++i) {
        int off = i * 4096 + tid * 16;
        int row = off >> 7, b = off & 127;
        gload16((const char*)g.A + (size_t)(m0 + row) * 2048 + (k0 << 1) + b,
                lA + i * 4096 + wave * 1024);
      }
    }
#pragma unroll
    for (int i = 0; i < BN / 32; ++i) {
      int off = i * 4096 + tid * 16;
      int row = off >> 7, b = off & 127;
      gload16((const char*)g.Bt + (size_t)(n0 + row) * 2048 + (k0 << 1) + b,
              lB + i * 4096 + wave * 1024);
    }
    __syncthreads();
#pragma unroll
    for (int kk = 0; kk < 2; ++kk) {
      bf16x8 af[MT], bfr[NT];
#pragma unroll
      for (int mt = 0; mt < MT; ++mt) {
        int row = wr * (BM / WR) + mt * 16 + lo;
        if (AF32) {
          int base = (row << 8) + ((kk << 7) + (hi << 5));
          int sw = (row & 7) << 4;
          f32x4 a0 = *(const f32x4*)(lA + ((base) ^ sw));
          f32x4 a1 = *(const f32x4*)(lA + ((base + 16) ^ sw));
          bf16x8 v;
#pragma unroll
          for (int j = 0; j < 4; ++j) { v[j] = (__bf16)a0[j]; v[4 + j] = (__bf16)a1[j]; }
          af[mt] = v;
        } else {
          int ob = (row << 7) + ((((kk << 2) + hi) << 4) ^ ((row & 7) << 4));
          af[mt] = *(const bf16x8*)(lA + ob);
        }
      }
#pragma unroll
      for (int nt = 0; nt < NT; ++nt) {
        int row = wc * (BN / WC) + nt * 16 + lo;
        int ob = (row << 7) + ((((kk << 2) + hi) << 4) ^ ((row & 7) << 4));
        bfr[nt] = *(const bf16x8*)(lB + ob);
      }
#pragma unroll
      for (int mt = 0; mt < MT; ++mt)
#pragma unroll
        for (int nt = 0; nt < NT; ++nt)
          acc[mt][nt] = mfma16(af[mt], bfr[nt], acc[mt][nt]);
    }
    __syncthreads();
  }

  // epilogue
#pragma unroll
  for (int mt = 0; mt < MT; ++mt) {
#pragma unroll
    for (int nt = 0; nt < NT; ++nt) {
      int col = n0 + wc * (BN / WC) + nt * 16 + lo;
      float bs = g.bias[col];
      int row0 = m0 + wr * (BM / WR) + mt * 16 + (hi << 2);
      float vj[4];
#pragma unroll
      for (int j = 0; j < 4; ++j) vj[j] = (acc[mt][nt][j] + bs) * g.scale;
      if (EPI == 1) {
#pragma unroll
        for (int j = 0; j < 4; ++j)
          ((float*)g.out)[(size_t)(row0 + j) * 1024 + col] = vj[j];
      } else if (blockIdx.z == 2) {
        // vt transposed (B,H,64,S): d=col&63, s=row0..row0+3 contiguous
        int d = col & 63;
        int bh = (row0 >> 11) * 16 + (col >> 6);
        int s = row0 & 2047;
        bf16x4 o;
#pragma unroll
        for (int j = 0; j < 4; ++j) o[j] = (__bf16)vj[j];
        char* p = (char*)g.out + ((size_t)bh << 18) + (size_t)d * 4096
                  + (s >> 6) * 128 + (((((s & 63) >> 3) ^ (d & 7)) << 4))
                  + ((s & 7) << 1);
        *(bf16x4*)p = o;
      } else {
        // head layout (B,H,S,64) swizzled
#pragma unroll
        for (int j = 0; j < 4; ++j) {
          int srow = row0 + j;
          size_t hb = ((size_t)((srow >> 11) * 16 + (col >> 6))) << 18;
          int ib = ((srow & 2047) << 7) + (((col & 63) << 1) ^ ((srow & 7) << 4));
          *(__bf16*)((char*)g.out + hb + ib) = (__bf16)vj[j];
        }
      }
    }
  }
}

// ---------------------------------------------------------------------------
// Fused attention (2-pass, no max-stabilization; scores pre-scaled by
// log2(e)/8 in the Q projection). R5: pass-1 double-buffers K staging using
// the idle vtl buffer with counted vmcnt + raw barriers.
// ---------------------------------------------------------------------------
__global__ __launch_bounds__(256, 4) void attn_k(
    const unsigned short* __restrict__ qh, const unsigned short* __restrict__ kh,
    const unsigned short* __restrict__ vt, const int* __restrict__ mask,
    float* __restrict__ attn, unsigned short* __restrict__ ctx) {
  constexpr int S = 2048;
  __shared__ unsigned short ktl[64 * 64];
  __shared__ unsigned short vtl[64 * 64];
  __shared__ unsigned long long mkb[32];
  __shared__ float pf[4][16 * 68];

  int tid = threadIdx.x, wave = tid >> 6, lane = tid & 63;
  int hi = lane >> 4, lo = lane & 15;
  int f = blockIdx.y * 32 + blockIdx.x;
  int xcd = f & 7, slot = f >> 3;
  int bh = xcd * 4 + (slot & 3);
  int qb = slot >> 2;
  int b = bh >> 4, h = bh & 15;
  const char* khead = (const char*)kh + ((size_t)bh << 18);
  const char* qhead = (const char*)qh + ((size_t)bh << 18);
  const char* vhead = (const char*)vt + ((size_t)bh << 18);

  for (int it = 0; it < 8; ++it) {
    unsigned long long bal = __ballot(mask[b * S + it * 256 + tid] != 0);
    if (lane == 0) mkb[it * 4 + wave] = bal;
  }
  __syncthreads();

  int q0 = qb * 64 + wave * 16;
  bf16x8 qf[2];
  {
    int row = q0 + lo;
#pragma unroll
    for (int kk = 0; kk < 2; ++kk) {
      int ib = (row << 7) + ((((kk << 2) + hi) << 4) ^ ((row & 7) << 4));
      qf[kk] = *(const bf16x8*)(qhead + ib);
    }
  }

  float lsum[4] = {0.f, 0.f, 0.f, 0.f};

  // ---- pass 1: row sums, double-buffered K staging (ktl/vtl ping-pong) ----
#pragma unroll
  for (int i = 0; i < 2; ++i)
    gload16(khead + i * 4096 + tid * 16, (char*)ktl + i * 4096 + wave * 1024);
  for (int kt = 0; kt < 32; ++kt) {
    const char* cb = (kt & 1) ? (const char*)vtl : (const char*)ktl;
    char* nb = (kt & 1) ? (char*)ktl : (char*)vtl;
    if (kt < 31) {
#pragma unroll
      for (int i = 0; i < 2; ++i)
        gload16(khead + (size_t)(kt + 1) * 8192 + i * 4096 + tid * 16,
                nb + i * 4096 + wave * 1024);
      asm volatile("s_waitcnt vmcnt(2)" ::: "memory");
    } else {
      asm volatile("s_waitcnt vmcnt(0)" ::: "memory");
    }
    __builtin_amdgcn_sched_barrier(0);
    __builtin_amdgcn_s_barrier();
    unsigned long long mw = mkb[kt];
    __builtin_amdgcn_s_setprio(1);
#pragma unroll
    for (int nt = 0; nt < 4; ++nt) {
      int r = nt * 16 + lo;
      f32x4 a = {0.f, 0.f, 0.f, 0.f};
#pragma unroll
      for (int kk = 0; kk < 2; ++kk) {
        int ob = (r << 7) + ((((kk << 2) + hi) << 4) ^ ((r & 7) << 4));
        a = mfma16(qf[kk], *(const bf16x8*)(cb + ob), a);
      }
      bool ok = (mw >> r) & 1ull;
#pragma unroll
      for (int j = 0; j < 4; ++j) lsum[j] += ok ? EXP2(a[j]) : 0.f;
    }
    __builtin_amdgcn_s_setprio(0);
    __builtin_amdgcn_s_barrier();
  }

  float rcp[4];
#pragma unroll
  for (int j = 0; j < 4; ++j) {
    float s = lsum[j];
    s += __shfl_xor(s, 1); s += __shfl_xor(s, 2);
    s += __shfl_xor(s, 4); s += __shfl_xor(s, 8);
    rcp[j] = s > 0.f ? 1.0f / s : 0.f;
  }

  f32x4 cacc[4];
#pragma unroll
  for (int nt = 0; nt < 4; ++nt) cacc[nt] = (f32x4){0.f, 0.f, 0.f, 0.f};

  float* arow = attn + (size_t)bh * S * S;
  float* pfw = pf[wave];

  // ---- pass 2: recompute, stage P in LDS, vector-store attn, PV ----
  for (int kt = 0; kt < 32; ++kt) {
#pragma unroll
    for (int i = 0; i < 2; ++i)
      gload16(khead + (size_t)kt * 8192 + i * 4096 + tid * 16,
              (char*)ktl + i * 4096 + wave * 1024);
#pragma unroll
    for (int i = 0; i < 2; ++i) {
      int off = i * 4096 + tid * 16;
      int d = off >> 7, x = off & 127;
      gload16(vhead + (size_t)d * 4096 + kt * 128 + x,
              (char*)vtl + i * 4096 + wave * 1024);
    }
    __syncthreads();
    unsigned long long mw = mkb[kt];
    __builtin_amdgcn_s_setprio(1);
#pragma unroll
    for (int nt = 0; nt < 4; ++nt) {
      int r = nt * 16 + lo;
      f32x4 a = {0.f, 0.f, 0.f, 0.f};
#pragma unroll
      for (int kk = 0; kk < 2; ++kk) {
        int ob = (r << 7) + ((((kk << 2) + hi) << 4) ^ ((r & 7) << 4));
        a = mfma16(qf[kk], *(const bf16x8*)((const char*)ktl + ob), a);
      }
      bool ok = (mw >> r) & 1ull;
#pragma unroll
      for (int j = 0; j < 4; ++j) {
        float pn = ok ? EXP2(a[j]) * rcp[j] : 0.f;
        pfw[((hi << 2) + j) * 68 + r] = pn;
      }
    }
    // PV: read normalized P back as bf16 fragments (same-wave DS ordering)
#pragma unroll
    for (int c = 0; c < 2; ++c) {
      f32x4 p0 = *(const f32x4*)&pfw[lo * 68 + c * 32 + hi * 8];
      f32x4 p1 = *(const f32x4*)&pfw[lo * 68 + c * 32 + hi * 8 + 4];
      bf16x8 pa;
#pragma unroll
      for (int i = 0; i < 4; ++i) { pa[i] = (__bf16)p0[i]; pa[4 + i] = (__bf16)p1[i]; }
#pragma unroll
      for (int nt = 0; nt < 4; ++nt) {
        int d = nt * 16 + lo;
        int ob = (d << 7) + ((((c << 2) + hi) << 4) ^ ((d & 7) << 4));
        cacc[nt] = mfma16(pa, *(const bf16x8*)((const char*)vtl + ob), cacc[nt]);
      }
    }
    __builtin_amdgcn_s_setprio(0);
    // attention store: 4 rows x 256B contiguous per dwordx4 instruction
    {
      int rsub = lane >> 4;        // 0..3
      int cb = (lane & 15) << 2;   // fp32 idx 0..60
#pragma unroll
      for (int s = 0; s < 4; ++s) {
        int row = s * 4 + rsub;
        f32x4 v = *(const f32x4*)&pfw[row * 68 + cb];
        __builtin_nontemporal_store(
            v, (f32x4*)(arow + (size_t)(q0 + row) * S + kt * 64 + cb));
      }
    }
    __syncthreads();
  }

  // context write, layout (B,S,1024) row-swizzled bf16 (already normalized)
#pragma unroll
  for (int nt = 0; nt < 4; ++nt) {
#pragma unroll
    for (int j = 0; j < 4; ++j) {
      int s = q0 + (hi << 2) + j;
      int mrow = b * S + s;
      int n = h * 64 + nt * 16 + lo;
      int ib = (n << 1) ^ ((mrow & 7) << 4);
      *(__bf16*)((char*)ctx + (size_t)mrow * 2048 + ib) = (__bf16)cacc[nt][j];
    }
  }
}

// ---------------------------------------------------------------------------
extern "C" void kernel_launch(void* const* d_in, const int* in_sizes, int n_in,
                              void* d_out, int out_size, void* d_ws, size_t ws_size,
                              hipStream_t stream) {
  const float* Q  = (const float*)d_in[0];
  const float* K  = (const float*)d_in[1];
  const float* V  = (const float*)d_in[2];
  const int* mask = (const int*)d_in[3];
  const float* WQ = (const float*)d_in[4];
  const float* bQ = (const float*)d_in[5];
  const float* WK = (const float*)d_in[6];
  const float* bK = (const float*)d_in[7];
  const float* WV = (const float*)d_in[8];
  const float* bV = (const float*)d_in[9];
  const float* WO = (const float*)d_in[10];
  const float* bO = (const float*)d_in[11];

  char* ws = (char*)d_ws;
  const size_t M1 = 1ull << 20;
  unsigned short* WQt = (unsigned short*)(ws + 0 * M1);
  unsigned short* WKt = (unsigned short*)(ws + 2 * M1);
  unsigned short* WVt = (unsigned short*)(ws + 4 * M1);
  unsigned short* WOt = (unsigned short*)(ws + 6 * M1);
  unsigned short* qh  = (unsigned short*)(ws + 8 * M1);
  unsigned short* kh  = (unsigned short*)(ws + 16 * M1);
  unsigned short* vt  = (unsigned short*)(ws + 24 * M1);
  unsigned short* ctx = (unsigned short*)(ws + 32 * M1);

  float* outF = (float*)d_out;                 // (B,S,1024) fp32
  float* attn = (float*)d_out + 4194304;       // (B,H,S,S) fp32

  dim3 blk(256);
  const float qscale = 0.125f * 1.44269504088896340736f;

  transW4<<<dim3(16, 16, 4), blk, 0, stream>>>(WQ, WK, WV, WO, WQt);

  GArg aq{Q, WQt, bQ, qh, qscale};
  GArg ak{K, WKt, bK, kh, 1.f};
  GArg av{V, WVt, bV, vt, 1.f};
  gemm_t<128, 128, 2, 2, 1, 0><<<dim3(32, 8, 3), blk, 0, stream>>>(aq, ak, av);

  attn_k<<<dim3(32, 32), blk, 0, stream>>>(qh, kh, vt, mask, attn, ctx);

  GArg ao{ctx, WOt, bO, outF, 1.f};
  gemm_t<64, 128, 1, 4, 0, 1><<<dim3(64, 8, 1), blk, 0, stream>>>(ao, ao, ao);
}